// Round 6
// baseline (661.414 us; speedup 1.0000x reference)
//
#include <hip/hip_runtime.h>
#include <hip/hip_bf16.h>

// RGCN gather-mm, etype-sorted edges.
// out[v][n] = sum_{e: dst[e]=v} sum_k feat[src[e]][k] * W[etype[e]][k][n]
//
// R6: counters show R4/R5 pinned at the TCC atomic-RMW ceiling (102.4M f32
// atomics = 291 G ops/s ~= 8 XCD x 16 ch x 2.4 GHz). Fewer atomic ops needs
// dst-aggregation needs workspace. We now BRANCH on ws_size (never checked
// before — R3's corruption was blind ws use):
//   fast path (ws >= ~213 MB): counting-sort by dst (3.2M int atomics) +
//     bf16 message materialization (plain streamed stores) + per-dst wave
//     reduction (plain stores). Removes the 102.4M-atomic wall.
//   fallback: R4 kernel verbatim (passed at 433 us).

#define TM 64             // edges per block (4 waves x 16 rows)
#define NTHREADS 256

typedef __attribute__((ext_vector_type(8))) __bf16 bf16x8;
typedef __attribute__((ext_vector_type(4))) float f32x4;

// ======================= shared MFMA body (macro) ==========================
// Computes acc0..acc3 (4x f32x4) for this lane's 16-edge x 64-out tile.
#define RGCN_MFMA_BODY                                                        \
    __shared__ __bf16 Wt[64 * 136];                                           \
    int b = blockIdx.x;                                                       \
    int e0 = b * TM;                                                          \
    int t = threadIdx.x;                                                      \
    int wave = t >> 6, lane = t & 63;                                         \
    int q = lane >> 4, m = lane & 15;                                         \
    int wbase = e0 + wave * 16;                                               \
    int last = e0 + TM - 1; if (last > E - 1) last = E - 1;                   \
    int rmin = etypes[e0];                                                    \
    int rmax = etypes[last];                                                  \
    int em = wbase + m;                                                       \
    bool rowok = em < E;                                                      \
    int ei = rowok ? em : E - 1;                                              \
    int my_et = rowok ? etypes[em] : -1;                                      \
    const float* arow = feat + (long)src[ei] * 128;                           \
    bf16x8 a[4];                                                              \
    _Pragma("unroll")                                                         \
    for (int ks = 0; ks < 4; ks++) {                                          \
        float4 fa = *(const float4*)(arow + ks * 32 + q * 8);                 \
        float4 fb = *(const float4*)(arow + ks * 32 + q * 8 + 4);             \
        bf16x8 v;                                                             \
        v[0] = (__bf16)fa.x; v[1] = (__bf16)fa.y;                             \
        v[2] = (__bf16)fa.z; v[3] = (__bf16)fa.w;                             \
        v[4] = (__bf16)fb.x; v[5] = (__bf16)fb.y;                             \
        v[6] = (__bf16)fb.z; v[7] = (__bf16)fb.w;                             \
        a[ks] = v;                                                            \
    }                                                                         \
    f32x4 acc0 = {0.f, 0.f, 0.f, 0.f};                                        \
    f32x4 acc1 = {0.f, 0.f, 0.f, 0.f};                                        \
    f32x4 acc2 = {0.f, 0.f, 0.f, 0.f};                                        \
    f32x4 acc3 = {0.f, 0.f, 0.f, 0.f};                                        \
    for (int r = rmin; r <= rmax; ++r) {                                      \
        if (r != rmin) __syncthreads();                                       \
        const float* wg = weight + (r << 13);                                 \
        for (int p = t; p < 4096; p += NTHREADS) {                            \
            int n = p & 63, kh = p >> 6;                                      \
            float w0 = wg[(kh * 2) * 64 + n];                                 \
            float w1 = wg[(kh * 2 + 1) * 64 + n];                             \
            union { unsigned u; __bf16 h[2]; } pk;                            \
            pk.h[0] = (__bf16)w0; pk.h[1] = (__bf16)w1;                       \
            *(unsigned*)&Wt[n * 136 + kh * 2] = pk.u;                         \
        }                                                                     \
        __syncthreads();                                                      \
        bool on = (my_et == r);                                               \
        _Pragma("unroll")                                                     \
        for (int ks = 0; ks < 4; ks++) {                                      \
            bf16x8 af = a[ks];                                                \
            if (!on) {                                                        \
                _Pragma("unroll")                                             \
                for (int j = 0; j < 8; j++) af[j] = (__bf16)0.f;              \
            }                                                                 \
            bf16x8 b0 = *(const bf16x8*)(&Wt[(0 * 16 + m) * 136 + ks * 32 + q * 8]); \
            bf16x8 b1 = *(const bf16x8*)(&Wt[(1 * 16 + m) * 136 + ks * 32 + q * 8]); \
            bf16x8 b2 = *(const bf16x8*)(&Wt[(2 * 16 + m) * 136 + ks * 32 + q * 8]); \
            bf16x8 b3 = *(const bf16x8*)(&Wt[(3 * 16 + m) * 136 + ks * 32 + q * 8]); \
            acc0 = __builtin_amdgcn_mfma_f32_16x16x32_bf16(af, b0, acc0, 0, 0, 0); \
            acc1 = __builtin_amdgcn_mfma_f32_16x16x32_bf16(af, b1, acc1, 0, 0, 0); \
            acc2 = __builtin_amdgcn_mfma_f32_16x16x32_bf16(af, b2, acc2, 0, 0, 0); \
            acc3 = __builtin_amdgcn_mfma_f32_16x16x32_bf16(af, b3, acc3, 0, 0, 0); \
        }                                                                     \
    }

// ---- fallback: R4 kernel (atomic scatter) ----
__global__ __launch_bounds__(NTHREADS)
void rgcn_atomic(const float* __restrict__ feat, const float* __restrict__ weight,
                 const int* __restrict__ src, const int* __restrict__ dst,
                 const int* __restrict__ etypes, int E,
                 float* __restrict__ out) {
    RGCN_MFMA_BODY
    #pragma unroll
    for (int reg = 0; reg < 4; reg++) {
        int er = wbase + q * 4 + reg;
        if (er < E) {
            float* orow = out + (long)dst[er] * 64;
            unsafeAtomicAdd(orow + 0 * 16 + m, acc0[reg]);
            unsafeAtomicAdd(orow + 1 * 16 + m, acc1[reg]);
            unsafeAtomicAdd(orow + 2 * 16 + m, acc2[reg]);
            unsafeAtomicAdd(orow + 3 * 16 + m, acc3[reg]);
        }
    }
}

// ---- fast path: message materialization (plain bf16 stores, no atomics) ----
__global__ __launch_bounds__(NTHREADS)
void rgcn_msg(const float* __restrict__ feat, const float* __restrict__ weight,
              const int* __restrict__ src, const int* __restrict__ etypes, int E,
              __bf16* __restrict__ msg) {
    RGCN_MFMA_BODY
    // C/D layout: col = lane&15 (m), row = q*4 + reg
    #pragma unroll
    for (int reg = 0; reg < 4; reg++) {
        int er = wbase + q * 4 + reg;
        if (er < E) {
            __bf16* mrow = msg + (size_t)er * 64;
            mrow[0 * 16 + m] = (__bf16)acc0[reg];
            mrow[1 * 16 + m] = (__bf16)acc1[reg];
            mrow[2 * 16 + m] = (__bf16)acc2[reg];
            mrow[3 * 16 + m] = (__bf16)acc3[reg];
        }
    }
}

// ---- counting sort by dst ----
__global__ void hist_kernel(const int* __restrict__ dst, int E, int* __restrict__ counts) {
    int e = blockIdx.x * 256 + threadIdx.x;
    if (e < E) atomicAdd(&counts[dst[e]], 1);
}

__global__ void scan1_kernel(const int* __restrict__ counts, int N, int* __restrict__ partial) {
    __shared__ int sm[256];
    int i = blockIdx.x * 256 + threadIdx.x;
    sm[threadIdx.x] = (i < N) ? counts[i] : 0;
    __syncthreads();
    for (int s = 128; s > 0; s >>= 1) {
        if (threadIdx.x < s) sm[threadIdx.x] += sm[threadIdx.x + s];
        __syncthreads();
    }
    if (threadIdx.x == 0) partial[blockIdx.x] = sm[0];
}

__global__ void scan2_kernel(int* __restrict__ partial, int NB,
                             int* __restrict__ offsets, int N, int E) {
    if (threadIdx.x == 0) {
        int run = 0;
        for (int b = 0; b < NB; b++) { int v = partial[b]; partial[b] = run; run += v; }
        offsets[N] = E;
    }
}

__global__ void scan3_kernel(const int* __restrict__ counts, const int* __restrict__ partial,
                             int N, int* __restrict__ offsets, int* __restrict__ cursor) {
    __shared__ int sm[256];
    int t = threadIdx.x, i = blockIdx.x * 256 + t;
    int v = (i < N) ? counts[i] : 0;
    sm[t] = v;
    __syncthreads();
    for (int s = 1; s < 256; s <<= 1) {          // inclusive Hillis-Steele
        int add = (t >= s) ? sm[t - s] : 0;
        __syncthreads();
        sm[t] += add;
        __syncthreads();
    }
    if (i < N) {
        int ex = partial[blockIdx.x] + sm[t] - v;  // exclusive
        offsets[i] = ex;
        cursor[i] = ex;
    }
}

__global__ void scatter_kernel(const int* __restrict__ dst, int E,
                               int* __restrict__ cursor, int* __restrict__ perm) {
    int e = blockIdx.x * 256 + threadIdx.x;
    if (e < E) {
        int pos = atomicAdd(&cursor[dst[e]], 1);
        perm[pos] = e;
    }
}

// ---- per-dst wave reduction: out[v][lane] = sum_j msg[perm[j]][lane] ----
__global__ __launch_bounds__(256)
void reduce_kernel(const int* __restrict__ offsets, const int* __restrict__ perm,
                   const __bf16* __restrict__ msg, int N, float* __restrict__ out) {
    int gid = blockIdx.x * 256 + threadIdx.x;
    int w = gid >> 6, lane = gid & 63;
    int nw = (gridDim.x * 256) >> 6;
    for (int v = w; v < N; v += nw) {
        int j0 = offsets[v], j1 = offsets[v + 1];
        float s = 0.f;
        int j = j0;
        for (; j + 1 < j1; j += 2) {           // unroll 2: overlap the loads
            int ea = perm[j], eb = perm[j + 1];
            float va = (float)msg[(size_t)ea * 64 + lane];
            float vb = (float)msg[(size_t)eb * 64 + lane];
            s += va + vb;
        }
        if (j < j1) s += (float)msg[(size_t)perm[j] * 64 + lane];
        out[(size_t)v * 64 + lane] = s;
    }
}

extern "C" void kernel_launch(void* const* d_in, const int* in_sizes, int n_in,
                              void* d_out, int out_size, void* d_ws, size_t ws_size,
                              hipStream_t stream) {
    const float* feat   = (const float*)d_in[0];
    const float* weight = (const float*)d_in[1];
    const int*   src    = (const int*)d_in[2];
    const int*   dst    = (const int*)d_in[3];
    const int*   etypes = (const int*)d_in[4];
    float* out = (float*)d_out;

    int E = in_sizes[2];
    int N = in_sizes[0] / 128;
    int NB = (N + 255) / 256;

    // ws layout (256B-aligned slabs)
    size_t o = 0;
    auto take = [&](size_t bytes) { size_t r = o; o = (o + bytes + 255) & ~(size_t)255; return r; };
    size_t o_counts  = take((size_t)(N + 1) * 4);
    size_t o_offsets = take((size_t)(N + 1) * 4);
    size_t o_cursor  = take((size_t)N * 4);
    size_t o_partial = take((size_t)NB * 4);
    size_t o_perm    = take((size_t)E * 4);
    size_t o_msg     = take((size_t)E * 64 * 2);
    size_t need = o;

    hipMemsetAsync(d_out, 0, (size_t)out_size * sizeof(float), stream);

    int egrid = (E + 255) / 256;
    int mgrid = (E + TM - 1) / TM;

    if (ws_size >= need) {
        char* ws = (char*)d_ws;
        int* counts  = (int*)(ws + o_counts);
        int* offsets = (int*)(ws + o_offsets);
        int* cursor  = (int*)(ws + o_cursor);
        int* partial = (int*)(ws + o_partial);
        int* perm    = (int*)(ws + o_perm);
        __bf16* msg  = (__bf16*)(ws + o_msg);

        hipMemsetAsync(counts, 0, (size_t)(N + 1) * 4, stream);
        hist_kernel<<<egrid, 256, 0, stream>>>(dst, E, counts);
        scan1_kernel<<<NB, 256, 0, stream>>>(counts, N, partial);
        scan2_kernel<<<1, 64, 0, stream>>>(partial, NB, offsets, N, E);
        scan3_kernel<<<NB, 256, 0, stream>>>(counts, partial, N, offsets, cursor);
        scatter_kernel<<<egrid, 256, 0, stream>>>(dst, E, cursor, perm);
        rgcn_msg<<<mgrid, NTHREADS, 0, stream>>>(feat, weight, src, etypes, E, msg);
        reduce_kernel<<<2048, 256, 0, stream>>>(offsets, perm, msg, N, out);
    } else {
        rgcn_atomic<<<mgrid, NTHREADS, 0, stream>>>(feat, weight, src, dst, etypes, E, out);
    }
}

// Round 7
// 464.390 us; speedup vs baseline: 1.4243x; 1.4243x over previous
//
#include <hip/hip_runtime.h>
#include <hip/hip_bf16.h>

// RGCN gather-mm, etype-sorted edges.
// out[v][n] = sum_{e: dst[e]=v} sum_k feat[src[e]][k] * W[etype[e]][k][n]
//
// R7: pipeline = counting-sort(dst) -> MFMA message kernel (writes bf16 msg
// rows at rank[e] = dst-sorted position; scattered WRITES, zero atomics on
// the fat data) -> segmented streaming reduce over contiguous msg ranges.
// R6 lessons: atomic-free msg kernel is 184us (vs 344 atomic), but perm-
// indirected reduce + single-threaded scan2 burned ~470us. Both fixed:
// rank-at-write makes reduce fully coalesced; scan2 is now a block scan.
// Fallback (ws too small): R4 atomic kernel (433us, known-good).

#define TM 64             // edges per block (4 waves x 16 rows)
#define NTHREADS 256

typedef __attribute__((ext_vector_type(8))) __bf16 bf16x8;
typedef __attribute__((ext_vector_type(4))) float f32x4;

// ======================= shared MFMA body (macro) ==========================
#define RGCN_MFMA_BODY                                                        \
    __shared__ __bf16 Wt[64 * 136];                                           \
    int b = blockIdx.x;                                                       \
    int e0 = b * TM;                                                          \
    int t = threadIdx.x;                                                      \
    int wave = t >> 6, lane = t & 63;                                         \
    int q = lane >> 4, m = lane & 15;                                         \
    int wbase = e0 + wave * 16;                                               \
    int last = e0 + TM - 1; if (last > E - 1) last = E - 1;                   \
    int rmin = etypes[e0];                                                    \
    int rmax = etypes[last];                                                  \
    int em = wbase + m;                                                       \
    bool rowok = em < E;                                                      \
    int ei = rowok ? em : E - 1;                                              \
    int my_et = rowok ? etypes[em] : -1;                                      \
    const float* arow = feat + (long)src[ei] * 128;                           \
    bf16x8 a[4];                                                              \
    _Pragma("unroll")                                                         \
    for (int ks = 0; ks < 4; ks++) {                                          \
        float4 fa = *(const float4*)(arow + ks * 32 + q * 8);                 \
        float4 fb = *(const float4*)(arow + ks * 32 + q * 8 + 4);             \
        bf16x8 v;                                                             \
        v[0] = (__bf16)fa.x; v[1] = (__bf16)fa.y;                             \
        v[2] = (__bf16)fa.z; v[3] = (__bf16)fa.w;                             \
        v[4] = (__bf16)fb.x; v[5] = (__bf16)fb.y;                             \
        v[6] = (__bf16)fb.z; v[7] = (__bf16)fb.w;                             \
        a[ks] = v;                                                            \
    }                                                                         \
    f32x4 acc0 = {0.f, 0.f, 0.f, 0.f};                                        \
    f32x4 acc1 = {0.f, 0.f, 0.f, 0.f};                                        \
    f32x4 acc2 = {0.f, 0.f, 0.f, 0.f};                                        \
    f32x4 acc3 = {0.f, 0.f, 0.f, 0.f};                                        \
    for (int r = rmin; r <= rmax; ++r) {                                      \
        if (r != rmin) __syncthreads();                                       \
        const float* wg = weight + (r << 13);                                 \
        for (int p = t; p < 4096; p += NTHREADS) {                            \
            int n = p & 63, kh = p >> 6;                                      \
            float w0 = wg[(kh * 2) * 64 + n];                                 \
            float w1 = wg[(kh * 2 + 1) * 64 + n];                             \
            union { unsigned u; __bf16 h[2]; } pk;                            \
            pk.h[0] = (__bf16)w0; pk.h[1] = (__bf16)w1;                       \
            *(unsigned*)&Wt[n * 136 + kh * 2] = pk.u;                         \
        }                                                                     \
        __syncthreads();                                                      \
        bool on = (my_et == r);                                               \
        _Pragma("unroll")                                                     \
        for (int ks = 0; ks < 4; ks++) {                                      \
            bf16x8 af = a[ks];                                                \
            if (!on) {                                                        \
                _Pragma("unroll")                                             \
                for (int j = 0; j < 8; j++) af[j] = (__bf16)0.f;              \
            }                                                                 \
            bf16x8 b0 = *(const bf16x8*)(&Wt[(0 * 16 + m) * 136 + ks * 32 + q * 8]); \
            bf16x8 b1 = *(const bf16x8*)(&Wt[(1 * 16 + m) * 136 + ks * 32 + q * 8]); \
            bf16x8 b2 = *(const bf16x8*)(&Wt[(2 * 16 + m) * 136 + ks * 32 + q * 8]); \
            bf16x8 b3 = *(const bf16x8*)(&Wt[(3 * 16 + m) * 136 + ks * 32 + q * 8]); \
            acc0 = __builtin_amdgcn_mfma_f32_16x16x32_bf16(af, b0, acc0, 0, 0, 0); \
            acc1 = __builtin_amdgcn_mfma_f32_16x16x32_bf16(af, b1, acc1, 0, 0, 0); \
            acc2 = __builtin_amdgcn_mfma_f32_16x16x32_bf16(af, b2, acc2, 0, 0, 0); \
            acc3 = __builtin_amdgcn_mfma_f32_16x16x32_bf16(af, b3, acc3, 0, 0, 0); \
        }                                                                     \
    }

// ---- fallback: atomic scatter (R4, known-good 433us) ----
__global__ __launch_bounds__(NTHREADS)
void rgcn_atomic(const float* __restrict__ feat, const float* __restrict__ weight,
                 const int* __restrict__ src, const int* __restrict__ dst,
                 const int* __restrict__ etypes, int E,
                 float* __restrict__ out) {
    RGCN_MFMA_BODY
    #pragma unroll
    for (int reg = 0; reg < 4; reg++) {
        int er = wbase + q * 4 + reg;
        if (er < E) {
            float* orow = out + (long)dst[er] * 64;
            unsafeAtomicAdd(orow + 0 * 16 + m, acc0[reg]);
            unsafeAtomicAdd(orow + 1 * 16 + m, acc1[reg]);
            unsafeAtomicAdd(orow + 2 * 16 + m, acc2[reg]);
            unsafeAtomicAdd(orow + 3 * 16 + m, acc3[reg]);
        }
    }
}

// ---- fast path: messages written at dst-sorted position rank[e] ----
__global__ __launch_bounds__(NTHREADS)
void rgcn_msg(const float* __restrict__ feat, const float* __restrict__ weight,
              const int* __restrict__ src, const int* __restrict__ etypes,
              const int* __restrict__ rank, int E,
              __bf16* __restrict__ msg) {
    RGCN_MFMA_BODY
    // C/D layout: col = lane&15 (m), row = q*4 + reg
    #pragma unroll
    for (int reg = 0; reg < 4; reg++) {
        int er = wbase + q * 4 + reg;
        if (er < E) {
            __bf16* mrow = msg + (size_t)rank[er] * 64;
            mrow[0 * 16 + m] = (__bf16)acc0[reg];
            mrow[1 * 16 + m] = (__bf16)acc1[reg];
            mrow[2 * 16 + m] = (__bf16)acc2[reg];
            mrow[3 * 16 + m] = (__bf16)acc3[reg];
        }
    }
}

// ---- counting sort by dst ----
__global__ void hist_kernel(const int* __restrict__ dst, int E, int* __restrict__ counts) {
    int e = blockIdx.x * 256 + threadIdx.x;
    if (e < E) atomicAdd(&counts[dst[e]], 1);
}

__global__ void scan1_kernel(const int* __restrict__ counts, int N, int* __restrict__ partial) {
    __shared__ int sm[256];
    int i = blockIdx.x * 256 + threadIdx.x;
    sm[threadIdx.x] = (i < N) ? counts[i] : 0;
    __syncthreads();
    for (int s = 128; s > 0; s >>= 1) {
        if (threadIdx.x < s) sm[threadIdx.x] += sm[threadIdx.x + s];
        __syncthreads();
    }
    if (threadIdx.x == 0) partial[blockIdx.x] = sm[0];
}

// block-parallel exclusive scan of the NB partials (NB <= 512 here)
__global__ void scan2_kernel(int* __restrict__ partial, int NB,
                             int* __restrict__ offsets, int N, int E) {
    __shared__ int sm[512];
    int t = threadIdx.x;
    int v = (t < NB) ? partial[t] : 0;
    sm[t] = v;
    __syncthreads();
    for (int s = 1; s < 512; s <<= 1) {
        int add = (t >= s) ? sm[t - s] : 0;
        __syncthreads();
        sm[t] += add;
        __syncthreads();
    }
    if (t < NB) partial[t] = sm[t] - v;   // exclusive
    if (t == 0) offsets[N] = E;
}

__global__ void scan3_kernel(const int* __restrict__ counts, const int* __restrict__ partial,
                             int N, int* __restrict__ offsets, int* __restrict__ cursor) {
    __shared__ int sm[256];
    int t = threadIdx.x, i = blockIdx.x * 256 + t;
    int v = (i < N) ? counts[i] : 0;
    sm[t] = v;
    __syncthreads();
    for (int s = 1; s < 256; s <<= 1) {          // inclusive Hillis-Steele
        int add = (t >= s) ? sm[t - s] : 0;
        __syncthreads();
        sm[t] += add;
        __syncthreads();
    }
    if (i < N) {
        int ex = partial[blockIdx.x] + sm[t] - v;  // exclusive
        offsets[i] = ex;
        cursor[i] = ex;
    }
}

__global__ void scatter_kernel(const int* __restrict__ dst, int E,
                               int* __restrict__ cursor, int* __restrict__ rank) {
    int e = blockIdx.x * 256 + threadIdx.x;
    if (e < E) {
        rank[e] = atomicAdd(&cursor[dst[e]], 1);
    }
}

// ---- segmented streaming reduce: msg rows [offsets[v], offsets[v+1]) ----
// wave per dst row; lane = (sub = lane>>3) x (c8 = lane&7): 8 rows x 16B
// in flight per iteration, all contiguous.
__global__ __launch_bounds__(256)
void reduce_kernel(const int* __restrict__ offsets, const __bf16* __restrict__ msg,
                   int N, float* __restrict__ out) {
    int gid = blockIdx.x * 256 + threadIdx.x;
    int w = gid >> 6, lane = gid & 63;
    int nw = (gridDim.x * 256) >> 6;
    int sub = lane >> 3, c8 = lane & 7;
    for (int v = w; v < N; v += nw) {
        int j0 = offsets[v], j1 = offsets[v + 1];
        float acc[8] = {0.f, 0.f, 0.f, 0.f, 0.f, 0.f, 0.f, 0.f};
        for (int j = j0 + sub; j < j1; j += 8) {
            bf16x8 val = *(const bf16x8*)(msg + (size_t)j * 64 + c8 * 8);
            #pragma unroll
            for (int i = 0; i < 8; i++) acc[i] += (float)val[i];
        }
        #pragma unroll
        for (int mask = 8; mask <= 32; mask <<= 1) {
            #pragma unroll
            for (int i = 0; i < 8; i++) acc[i] += __shfl_xor(acc[i], mask, 64);
        }
        if (sub == 0) {
            float4 lo = {acc[0], acc[1], acc[2], acc[3]};
            float4 hi = {acc[4], acc[5], acc[6], acc[7]};
            *(float4*)(out + (size_t)v * 64 + c8 * 8) = lo;
            *(float4*)(out + (size_t)v * 64 + c8 * 8 + 4) = hi;
        }
    }
}

extern "C" void kernel_launch(void* const* d_in, const int* in_sizes, int n_in,
                              void* d_out, int out_size, void* d_ws, size_t ws_size,
                              hipStream_t stream) {
    const float* feat   = (const float*)d_in[0];
    const float* weight = (const float*)d_in[1];
    const int*   src    = (const int*)d_in[2];
    const int*   dst    = (const int*)d_in[3];
    const int*   etypes = (const int*)d_in[4];
    float* out = (float*)d_out;

    int E = in_sizes[2];
    int N = in_sizes[0] / 128;
    int NB = (N + 255) / 256;

    // ws layout (256B-aligned slabs)
    size_t o = 0;
    auto take = [&](size_t bytes) { size_t r = o; o = (o + bytes + 255) & ~(size_t)255; return r; };
    size_t o_counts  = take((size_t)(N + 1) * 4);
    size_t o_offsets = take((size_t)(N + 1) * 4);
    size_t o_cursor  = take((size_t)N * 4);
    size_t o_partial = take((size_t)NB * 4);
    size_t o_rank    = take((size_t)E * 4);
    size_t o_msg     = take((size_t)E * 64 * 2);
    size_t need = o;

    int egrid = (E + 255) / 256;
    int mgrid = (E + TM - 1) / TM;

    if (ws_size >= need && NB <= 512) {
        char* ws = (char*)d_ws;
        int* counts  = (int*)(ws + o_counts);
        int* offsets = (int*)(ws + o_offsets);
        int* cursor  = (int*)(ws + o_cursor);
        int* partial = (int*)(ws + o_partial);
        int* rank    = (int*)(ws + o_rank);
        __bf16* msg  = (__bf16*)(ws + o_msg);

        hipMemsetAsync(counts, 0, (size_t)(N + 1) * 4, stream);
        hist_kernel<<<egrid, 256, 0, stream>>>(dst, E, counts);
        scan1_kernel<<<NB, 256, 0, stream>>>(counts, N, partial);
        scan2_kernel<<<1, 512, 0, stream>>>(partial, NB, offsets, N, E);
        scan3_kernel<<<NB, 256, 0, stream>>>(counts, partial, N, offsets, cursor);
        scatter_kernel<<<egrid, 256, 0, stream>>>(dst, E, cursor, rank);
        rgcn_msg<<<mgrid, NTHREADS, 0, stream>>>(feat, weight, src, etypes, rank, E, msg);
        reduce_kernel<<<2048, 256, 0, stream>>>(offsets, msg, N, out);
    } else {
        hipMemsetAsync(d_out, 0, (size_t)out_size * sizeof(float), stream);
        rgcn_atomic<<<mgrid, NTHREADS, 0, stream>>>(feat, weight, src, dst, etypes, E, out);
    }
}

// Round 8
// 406.280 us; speedup vs baseline: 1.6280x; 1.1430x over previous
//
#include <hip/hip_runtime.h>
#include <hip/hip_bf16.h>

// RGCN gather-mm, etype-sorted edges.
// out[v][n] = sum_{e: dst[e]=v} sum_k feat[src[e]][k] * W[etype[e]][k][n]
//
// R8 pipeline: counting-sort(dst) -> bf16 cvt of feat/W -> MFMA message
// kernel (bf16 feat gather, pre-transposed bf16 W, packed 8B NT msg stores
// in permuted layout c'=m*4+nt) -> segmented streaming reduce (un-permutes
// at final out write). Tiered fallbacks on ws_size.

#define TM 64             // edges per block (4 waves x 16 rows)
#define NTHREADS 256

typedef __attribute__((ext_vector_type(8))) __bf16 bf16x8;
typedef __attribute__((ext_vector_type(4))) float f32x4;

// ---- cvt: feat fp32 -> bf16 ----
__global__ void cvt_feat_kernel(const float* __restrict__ f,
                                __bf16* __restrict__ o, int n) {
    int i = (blockIdx.x * 256 + threadIdx.x) * 8;
    if (i >= n) return;
    float4 a = *(const float4*)(f + i);
    float4 b = *(const float4*)(f + i + 4);
    bf16x8 v;
    v[0] = (__bf16)a.x; v[1] = (__bf16)a.y; v[2] = (__bf16)a.z; v[3] = (__bf16)a.w;
    v[4] = (__bf16)b.x; v[5] = (__bf16)b.y; v[6] = (__bf16)b.z; v[7] = (__bf16)b.w;
    *(bf16x8*)(o + i) = v;
}

// ---- cvt: W [R][128][64] fp32 -> Wt [R][64][128] bf16 (transposed) ----
__global__ void cvt_w_kernel(const float* __restrict__ w,
                             __bf16* __restrict__ o, int total) {
    int idx = blockIdx.x * 256 + threadIdx.x;
    if (idx >= total) return;
    int r = idx >> 13;
    int rem = idx & 8191;
    int k = rem >> 6;         // d_in
    int n = rem & 63;         // d_out
    o[(r << 13) + (n << 7) + k] = (__bf16)w[idx];
}

// ============ fast path: message kernel (templated on feat dtype) =========
template<bool BF>
__global__ __launch_bounds__(NTHREADS)
void rgcn_msg(const void* __restrict__ featp, const __bf16* __restrict__ wtb,
              const int* __restrict__ src, const int* __restrict__ etypes,
              const int* __restrict__ rank, int E,
              __bf16* __restrict__ msg) {
    __shared__ __bf16 Wt[64 * 136];   // [n][k], k padded ->136

    int b = blockIdx.x;
    int e0 = b * TM;
    int t = threadIdx.x;
    int wave = t >> 6, lane = t & 63;
    int q = lane >> 4, m = lane & 15;
    int wbase = e0 + wave * 16;

    int last = e0 + TM - 1; if (last > E - 1) last = E - 1;
    int rmin = etypes[e0];
    int rmax = etypes[last];

    int em = wbase + m;
    bool rowok = em < E;
    int ei = rowok ? em : E - 1;
    int my_et = rowok ? etypes[em] : -1;

    bf16x8 a[4];
    if (BF) {
        const __bf16* arow = (const __bf16*)featp + (long)src[ei] * 128;
        #pragma unroll
        for (int ks = 0; ks < 4; ks++)
            a[ks] = *(const bf16x8*)(arow + ks * 32 + q * 8);
    } else {
        const float* arow = (const float*)featp + (long)src[ei] * 128;
        #pragma unroll
        for (int ks = 0; ks < 4; ks++) {
            float4 fa = *(const float4*)(arow + ks * 32 + q * 8);
            float4 fb = *(const float4*)(arow + ks * 32 + q * 8 + 4);
            bf16x8 v;
            v[0] = (__bf16)fa.x; v[1] = (__bf16)fa.y;
            v[2] = (__bf16)fa.z; v[3] = (__bf16)fa.w;
            v[4] = (__bf16)fb.x; v[5] = (__bf16)fb.y;
            v[6] = (__bf16)fb.z; v[7] = (__bf16)fb.w;
            a[ks] = v;
        }
    }

    f32x4 acc0 = {0.f, 0.f, 0.f, 0.f};
    f32x4 acc1 = {0.f, 0.f, 0.f, 0.f};
    f32x4 acc2 = {0.f, 0.f, 0.f, 0.f};
    f32x4 acc3 = {0.f, 0.f, 0.f, 0.f};

    for (int r = rmin; r <= rmax; ++r) {
        if (r != rmin) __syncthreads();
        // stage pre-transposed bf16 W[r] (64x128 = 16KB): 1024 8-elem chunks
        const __bf16* wg = wtb + (r << 13);
        #pragma unroll
        for (int c = t; c < 1024; c += NTHREADS) {
            int n = c >> 4, kc = c & 15;
            *(bf16x8*)(&Wt[n * 136 + kc * 8]) = *(const bf16x8*)(wg + n * 128 + kc * 8);
        }
        __syncthreads();

        bool on = (my_et == r);
        #pragma unroll
        for (int ks = 0; ks < 4; ks++) {
            bf16x8 af = a[ks];
            if (!on) {
                #pragma unroll
                for (int j = 0; j < 8; j++) af[j] = (__bf16)0.f;
            }
            bf16x8 b0 = *(const bf16x8*)(&Wt[(0 * 16 + m) * 136 + ks * 32 + q * 8]);
            bf16x8 b1 = *(const bf16x8*)(&Wt[(1 * 16 + m) * 136 + ks * 32 + q * 8]);
            bf16x8 b2 = *(const bf16x8*)(&Wt[(2 * 16 + m) * 136 + ks * 32 + q * 8]);
            bf16x8 b3 = *(const bf16x8*)(&Wt[(3 * 16 + m) * 136 + ks * 32 + q * 8]);
            acc0 = __builtin_amdgcn_mfma_f32_16x16x32_bf16(af, b0, acc0, 0, 0, 0);
            acc1 = __builtin_amdgcn_mfma_f32_16x16x32_bf16(af, b1, acc1, 0, 0, 0);
            acc2 = __builtin_amdgcn_mfma_f32_16x16x32_bf16(af, b2, acc2, 0, 0, 0);
            acc3 = __builtin_amdgcn_mfma_f32_16x16x32_bf16(af, b3, acc3, 0, 0, 0);
        }
    }

    // C/D layout: col = lane&15 (m), row = q*4 + reg.
    // msg stored PERMUTED: msg[p][c'] with c' = m*4 + nt  (col = nt*16+m).
    // One packed 8B NT store per row per lane (was 4x2B scalar).
    #pragma unroll
    for (int reg = 0; reg < 4; reg++) {
        int er = wbase + q * 4 + reg;
        if (er < E) {
            int p = rank[er];
            union { unsigned long long u; __bf16 h[4]; } pk;
            pk.h[0] = (__bf16)acc0[reg];
            pk.h[1] = (__bf16)acc1[reg];
            pk.h[2] = (__bf16)acc2[reg];
            pk.h[3] = (__bf16)acc3[reg];
            __builtin_nontemporal_store(pk.u,
                (unsigned long long*)(msg + (size_t)p * 64 + m * 4));
        }
    }
}

// ---- fallback: atomic scatter (R4, known-good 433us; no ws use) ----
__global__ __launch_bounds__(NTHREADS)
void rgcn_atomic(const float* __restrict__ feat, const float* __restrict__ weight,
                 const int* __restrict__ src, const int* __restrict__ dst,
                 const int* __restrict__ etypes, int E,
                 float* __restrict__ out) {
    __shared__ __bf16 Wt[64 * 136];
    int b = blockIdx.x;
    int e0 = b * TM;
    int t = threadIdx.x;
    int wave = t >> 6, lane = t & 63;
    int q = lane >> 4, m = lane & 15;
    int wbase = e0 + wave * 16;
    int last = e0 + TM - 1; if (last > E - 1) last = E - 1;
    int rmin = etypes[e0];
    int rmax = etypes[last];
    int em = wbase + m;
    bool rowok = em < E;
    int ei = rowok ? em : E - 1;
    int my_et = rowok ? etypes[em] : -1;
    const float* arow = feat + (long)src[ei] * 128;
    bf16x8 a[4];
    #pragma unroll
    for (int ks = 0; ks < 4; ks++) {
        float4 fa = *(const float4*)(arow + ks * 32 + q * 8);
        float4 fb = *(const float4*)(arow + ks * 32 + q * 8 + 4);
        bf16x8 v;
        v[0] = (__bf16)fa.x; v[1] = (__bf16)fa.y;
        v[2] = (__bf16)fa.z; v[3] = (__bf16)fa.w;
        v[4] = (__bf16)fb.x; v[5] = (__bf16)fb.y;
        v[6] = (__bf16)fb.z; v[7] = (__bf16)fb.w;
        a[ks] = v;
    }
    f32x4 acc0 = {0.f, 0.f, 0.f, 0.f};
    f32x4 acc1 = {0.f, 0.f, 0.f, 0.f};
    f32x4 acc2 = {0.f, 0.f, 0.f, 0.f};
    f32x4 acc3 = {0.f, 0.f, 0.f, 0.f};
    for (int r = rmin; r <= rmax; ++r) {
        if (r != rmin) __syncthreads();
        const float* wg = weight + (r << 13);
        for (int p = t; p < 4096; p += NTHREADS) {
            int n = p & 63, kh = p >> 6;
            float w0 = wg[(kh * 2) * 64 + n];
            float w1 = wg[(kh * 2 + 1) * 64 + n];
            union { unsigned u; __bf16 h[2]; } pk;
            pk.h[0] = (__bf16)w0; pk.h[1] = (__bf16)w1;
            *(unsigned*)&Wt[n * 136 + kh * 2] = pk.u;
        }
        __syncthreads();
        bool on = (my_et == r);
        #pragma unroll
        for (int ks = 0; ks < 4; ks++) {
            bf16x8 af = a[ks];
            if (!on) {
                #pragma unroll
                for (int j = 0; j < 8; j++) af[j] = (__bf16)0.f;
            }
            bf16x8 b0 = *(const bf16x8*)(&Wt[(0 * 16 + m) * 136 + ks * 32 + q * 8]);
            bf16x8 b1 = *(const bf16x8*)(&Wt[(1 * 16 + m) * 136 + ks * 32 + q * 8]);
            bf16x8 b2 = *(const bf16x8*)(&Wt[(2 * 16 + m) * 136 + ks * 32 + q * 8]);
            bf16x8 b3 = *(const bf16x8*)(&Wt[(3 * 16 + m) * 136 + ks * 32 + q * 8]);
            acc0 = __builtin_amdgcn_mfma_f32_16x16x32_bf16(af, b0, acc0, 0, 0, 0);
            acc1 = __builtin_amdgcn_mfma_f32_16x16x32_bf16(af, b1, acc1, 0, 0, 0);
            acc2 = __builtin_amdgcn_mfma_f32_16x16x32_bf16(af, b2, acc2, 0, 0, 0);
            acc3 = __builtin_amdgcn_mfma_f32_16x16x32_bf16(af, b3, acc3, 0, 0, 0);
        }
    }
    #pragma unroll
    for (int reg = 0; reg < 4; reg++) {
        int er = wbase + q * 4 + reg;
        if (er < E) {
            float* orow = out + (long)dst[er] * 64;
            unsafeAtomicAdd(orow + 0 * 16 + m, acc0[reg]);
            unsafeAtomicAdd(orow + 1 * 16 + m, acc1[reg]);
            unsafeAtomicAdd(orow + 2 * 16 + m, acc2[reg]);
            unsafeAtomicAdd(orow + 3 * 16 + m, acc3[reg]);
        }
    }
}

// ---- counting sort by dst ----
__global__ void hist_kernel(const int* __restrict__ dst, int E, int* __restrict__ counts) {
    int e = blockIdx.x * 256 + threadIdx.x;
    if (e < E) atomicAdd(&counts[dst[e]], 1);
}

__global__ void scan1_kernel(const int* __restrict__ counts, int N, int* __restrict__ partial) {
    __shared__ int sm[256];
    int i = blockIdx.x * 256 + threadIdx.x;
    sm[threadIdx.x] = (i < N) ? counts[i] : 0;
    __syncthreads();
    for (int s = 128; s > 0; s >>= 1) {
        if (threadIdx.x < s) sm[threadIdx.x] += sm[threadIdx.x + s];
        __syncthreads();
    }
    if (threadIdx.x == 0) partial[blockIdx.x] = sm[0];
}

__global__ void scan2_kernel(int* __restrict__ partial, int NB,
                             int* __restrict__ offsets, int N, int E) {
    __shared__ int sm[512];
    int t = threadIdx.x;
    int v = (t < NB) ? partial[t] : 0;
    sm[t] = v;
    __syncthreads();
    for (int s = 1; s < 512; s <<= 1) {
        int add = (t >= s) ? sm[t - s] : 0;
        __syncthreads();
        sm[t] += add;
        __syncthreads();
    }
    if (t < NB) partial[t] = sm[t] - v;   // exclusive
    if (t == 0) offsets[N] = E;
}

__global__ void scan3_kernel(const int* __restrict__ counts, const int* __restrict__ partial,
                             int N, int* __restrict__ offsets, int* __restrict__ cursor) {
    __shared__ int sm[256];
    int t = threadIdx.x, i = blockIdx.x * 256 + t;
    int v = (i < N) ? counts[i] : 0;
    sm[t] = v;
    __syncthreads();
    for (int s = 1; s < 256; s <<= 1) {
        int add = (t >= s) ? sm[t - s] : 0;
        __syncthreads();
        sm[t] += add;
        __syncthreads();
    }
    if (i < N) {
        int ex = partial[blockIdx.x] + sm[t] - v;  // exclusive
        offsets[i] = ex;
        cursor[i] = ex;
    }
}

__global__ void scatter_kernel(const int* __restrict__ dst, int E,
                               int* __restrict__ cursor, int* __restrict__ rank) {
    int e = blockIdx.x * 256 + threadIdx.x;
    if (e < E) rank[e] = atomicAdd(&cursor[dst[e]], 1);
}

// ---- segmented streaming reduce over permuted msg rows ----
// msg[p][c'], c' = m*4+nt, col(c') = (c'&3)*16 + (c'>>2).
__global__ __launch_bounds__(256)
void reduce_kernel(const int* __restrict__ offsets, const __bf16* __restrict__ msg,
                   int N, float* __restrict__ out) {
    int gid = blockIdx.x * 256 + threadIdx.x;
    int w = gid >> 6, lane = gid & 63;
    int nw = (gridDim.x * 256) >> 6;
    int sub = lane >> 3, c8 = lane & 7;
    for (int v = w; v < N; v += nw) {
        int j0 = offsets[v], j1 = offsets[v + 1];
        float acc[8] = {0.f, 0.f, 0.f, 0.f, 0.f, 0.f, 0.f, 0.f};
        for (int j = j0 + sub; j < j1; j += 8) {
            bf16x8 val = __builtin_nontemporal_load(
                (const bf16x8*)(msg + (size_t)j * 64 + c8 * 8));
            #pragma unroll
            for (int i = 0; i < 8; i++) acc[i] += (float)val[i];
        }
        #pragma unroll
        for (int mask = 8; mask <= 32; mask <<= 1) {
            #pragma unroll
            for (int i = 0; i < 8; i++) acc[i] += __shfl_xor(acc[i], mask, 64);
        }
        if (sub == 0) {
            float* orow = out + (size_t)v * 64;
            #pragma unroll
            for (int i = 0; i < 8; i++) {
                int cp = c8 * 8 + i;
                orow[(cp & 3) * 16 + (cp >> 2)] = acc[i];
            }
        }
    }
}

extern "C" void kernel_launch(void* const* d_in, const int* in_sizes, int n_in,
                              void* d_out, int out_size, void* d_ws, size_t ws_size,
                              hipStream_t stream) {
    const float* feat   = (const float*)d_in[0];
    const float* weight = (const float*)d_in[1];
    const int*   src    = (const int*)d_in[2];
    const int*   dst    = (const int*)d_in[3];
    const int*   etypes = (const int*)d_in[4];
    float* out = (float*)d_out;

    int nfeat = in_sizes[0];
    int nw    = in_sizes[1];
    int E     = in_sizes[2];
    int N     = nfeat / 128;
    int NB    = (N + 255) / 256;

    // ws layout (256B-aligned slabs)
    size_t o = 0;
    auto take = [&](size_t bytes) { size_t r = o; o = (o + bytes + 255) & ~(size_t)255; return r; };
    size_t o_counts  = take((size_t)(N + 1) * 4);
    size_t o_offsets = take((size_t)(N + 1) * 4);
    size_t o_cursor  = take((size_t)N * 4);
    size_t o_partial = take((size_t)NB * 4);
    size_t o_rank    = take((size_t)E * 4);
    size_t o_wtb     = take((size_t)nw * 2);
    size_t o_msg     = take((size_t)E * 64 * 2);
    size_t need_base = o;
    size_t o_featb   = take((size_t)nfeat * 2);
    size_t need_full = o;

    int egrid = (E + 255) / 256;
    int mgrid = (E + TM - 1) / TM;

    if (ws_size >= need_base && NB <= 512) {
        char* ws = (char*)d_ws;
        int* counts  = (int*)(ws + o_counts);
        int* offsets = (int*)(ws + o_offsets);
        int* cursor  = (int*)(ws + o_cursor);
        int* partial = (int*)(ws + o_partial);
        int* rank    = (int*)(ws + o_rank);
        __bf16* wtb  = (__bf16*)(ws + o_wtb);
        __bf16* msg  = (__bf16*)(ws + o_msg);

        hipMemsetAsync(counts, 0, (size_t)(N + 1) * 4, stream);
        hist_kernel<<<egrid, 256, 0, stream>>>(dst, E, counts);
        scan1_kernel<<<NB, 256, 0, stream>>>(counts, N, partial);
        scan2_kernel<<<1, 512, 0, stream>>>(partial, NB, offsets, N, E);
        scan3_kernel<<<NB, 256, 0, stream>>>(counts, partial, N, offsets, cursor);
        scatter_kernel<<<egrid, 256, 0, stream>>>(dst, E, cursor, rank);
        cvt_w_kernel<<<(nw + 255) / 256, 256, 0, stream>>>(weight, wtb, nw);

        if (ws_size >= need_full) {
            __bf16* featb = (__bf16*)(ws + o_featb);
            cvt_feat_kernel<<<(nfeat / 8 + 255) / 256, 256, 0, stream>>>(feat, featb, nfeat);
            rgcn_msg<true><<<mgrid, NTHREADS, 0, stream>>>(featb, wtb, src, etypes, rank, E, msg);
        } else {
            rgcn_msg<false><<<mgrid, NTHREADS, 0, stream>>>(feat, wtb, src, etypes, rank, E, msg);
        }
        reduce_kernel<<<2048, 256, 0, stream>>>(offsets, msg, N, out);
    } else {
        hipMemsetAsync(d_out, 0, (size_t)out_size * sizeof(float), stream);
        rgcn_atomic<<<mgrid, NTHREADS, 0, stream>>>(feat, weight, src, dst, etypes, E, out);
    }
}

// Round 9
// 402.183 us; speedup vs baseline: 1.6446x; 1.0102x over previous
//
#include <hip/hip_runtime.h>
#include <hip/hip_bf16.h>

// RGCN gather-mm, etype-sorted edges.
// out[v][n] = sum_{e: dst[e]=v} sum_k feat[src[e]][k] * W[etype[e]][k][n]
//
// R9: replace per-edge MFMA (re-gathers feat per edge, 410MB logical) with
// the dense projection: proj[r] = feat @ W[r] for all 16 relations
// (E = R*N exactly -> identical 26.2 GFLOP, zero gather, feat read once/rel
// from L3). Then a single dst-sorted segmented reduce gathers proj rows via
// pidx[p] = etype*N+src (written at scatter time). Deletes the 126us msg
// kernel + its 200MB msg write + 200MB re-read.
// proj rows stored in R8's verified permuted layout c' = m*4+nt.

#define NTHREADS 256

typedef __attribute__((ext_vector_type(8))) __bf16 bf16x8;
typedef __attribute__((ext_vector_type(4))) float f32x4;

// ---- cvt: feat fp32 -> bf16 ----
__global__ void cvt_feat_kernel(const float* __restrict__ f,
                                __bf16* __restrict__ o, int n) {
    int i = (blockIdx.x * 256 + threadIdx.x) * 8;
    if (i >= n) return;
    float4 a = *(const float4*)(f + i);
    float4 b = *(const float4*)(f + i + 4);
    bf16x8 v;
    v[0] = (__bf16)a.x; v[1] = (__bf16)a.y; v[2] = (__bf16)a.z; v[3] = (__bf16)a.w;
    v[4] = (__bf16)b.x; v[5] = (__bf16)b.y; v[6] = (__bf16)b.z; v[7] = (__bf16)b.w;
    *(bf16x8*)(o + i) = v;
}

// ---- cvt: W [R][128][64] fp32 -> Wt [R][64][128] bf16 (transposed) ----
__global__ void cvt_w_kernel(const float* __restrict__ w,
                             __bf16* __restrict__ o, int total) {
    int idx = blockIdx.x * 256 + threadIdx.x;
    if (idx >= total) return;
    int r = idx >> 13;
    int rem = idx & 8191;
    int k = rem >> 6;         // d_in
    int n = rem & 63;         // d_out
    o[(r << 13) + (n << 7) + k] = (__bf16)w[idx];
}

// ---- dense projection: proj[r][node][c'] = (feat @ W[r]) permuted ----
// grid (ceil(N/128), R); block 256 = 4 waves; wave handles 32 nodes x 64 outs.
__global__ __launch_bounds__(NTHREADS)
void proj_kernel(const __bf16* __restrict__ featb, const __bf16* __restrict__ wtb,
                 int N, __bf16* __restrict__ projb) {
    __shared__ __bf16 Wt[64 * 136];   // [n][k], k padded ->136

    int r = blockIdx.y;
    int t = threadIdx.x;
    // stage pre-transposed bf16 W[r] (64x128 = 16KB)
    const __bf16* wg = wtb + (r << 13);
    #pragma unroll
    for (int c = t; c < 1024; c += NTHREADS) {
        int n = c >> 4, kc = c & 15;
        *(bf16x8*)(&Wt[n * 136 + kc * 8]) = *(const bf16x8*)(wg + n * 128 + kc * 8);
    }
    __syncthreads();

    int wave = t >> 6, lane = t & 63;
    int q = lane >> 4, m = lane & 15;
    long node0 = (long)blockIdx.x * 128 + wave * 32;   // wave's first node

    // A frags: mt in {0,1}; load row node0+mt*16+m (clamped; masked at store)
    bf16x8 a[2][4];
    #pragma unroll
    for (int mt = 0; mt < 2; mt++) {
        long nd = node0 + mt * 16 + m;
        if (nd > N - 1) nd = N - 1;
        const __bf16* arow = featb + nd * 128;
        #pragma unroll
        for (int ks = 0; ks < 4; ks++)
            a[mt][ks] = *(const bf16x8*)(arow + ks * 32 + q * 8);
    }

    f32x4 acc[2][4] = {};   // [mt][nt]
    #pragma unroll
    for (int ks = 0; ks < 4; ks++) {
        bf16x8 b0 = *(const bf16x8*)(&Wt[(0 * 16 + m) * 136 + ks * 32 + q * 8]);
        bf16x8 b1 = *(const bf16x8*)(&Wt[(1 * 16 + m) * 136 + ks * 32 + q * 8]);
        bf16x8 b2 = *(const bf16x8*)(&Wt[(2 * 16 + m) * 136 + ks * 32 + q * 8]);
        bf16x8 b3 = *(const bf16x8*)(&Wt[(3 * 16 + m) * 136 + ks * 32 + q * 8]);
        #pragma unroll
        for (int mt = 0; mt < 2; mt++) {
            acc[mt][0] = __builtin_amdgcn_mfma_f32_16x16x32_bf16(a[mt][ks], b0, acc[mt][0], 0, 0, 0);
            acc[mt][1] = __builtin_amdgcn_mfma_f32_16x16x32_bf16(a[mt][ks], b1, acc[mt][1], 0, 0, 0);
            acc[mt][2] = __builtin_amdgcn_mfma_f32_16x16x32_bf16(a[mt][ks], b2, acc[mt][2], 0, 0, 0);
            acc[mt][3] = __builtin_amdgcn_mfma_f32_16x16x32_bf16(a[mt][ks], b3, acc[mt][3], 0, 0, 0);
        }
    }

    // C/D: col = nt*16 + m, row(node) = mt*16 + q*4 + reg.
    // Permuted row layout c' = m*4 + nt -> one packed 8B store per node/lane.
    #pragma unroll
    for (int mt = 0; mt < 2; mt++) {
        #pragma unroll
        for (int reg = 0; reg < 4; reg++) {
            long nd = node0 + mt * 16 + q * 4 + reg;
            if (nd < N) {
                union { unsigned long long u; __bf16 h[4]; } pk;
                pk.h[0] = (__bf16)acc[mt][0][reg];
                pk.h[1] = (__bf16)acc[mt][1][reg];
                pk.h[2] = (__bf16)acc[mt][2][reg];
                pk.h[3] = (__bf16)acc[mt][3][reg];
                *(unsigned long long*)(projb + ((size_t)r * N + nd) * 64 + m * 4) = pk.u;
            }
        }
    }
}

// ---- counting sort by dst ----
__global__ void hist_kernel(const int* __restrict__ dst, int E, int* __restrict__ counts) {
    int e = blockIdx.x * 256 + threadIdx.x;
    if (e < E) atomicAdd(&counts[dst[e]], 1);
}

__global__ void scan1_kernel(const int* __restrict__ counts, int N, int* __restrict__ partial) {
    __shared__ int sm[256];
    int i = blockIdx.x * 256 + threadIdx.x;
    sm[threadIdx.x] = (i < N) ? counts[i] : 0;
    __syncthreads();
    for (int s = 128; s > 0; s >>= 1) {
        if (threadIdx.x < s) sm[threadIdx.x] += sm[threadIdx.x + s];
        __syncthreads();
    }
    if (threadIdx.x == 0) partial[blockIdx.x] = sm[0];
}

__global__ void scan2_kernel(int* __restrict__ partial, int NB,
                             int* __restrict__ offsets, int N, int E) {
    __shared__ int sm[512];
    int t = threadIdx.x;
    int v = (t < NB) ? partial[t] : 0;
    sm[t] = v;
    __syncthreads();
    for (int s = 1; s < 512; s <<= 1) {
        int add = (t >= s) ? sm[t - s] : 0;
        __syncthreads();
        sm[t] += add;
        __syncthreads();
    }
    if (t < NB) partial[t] = sm[t] - v;   // exclusive
    if (t == 0) offsets[N] = E;
}

__global__ void scan3_kernel(const int* __restrict__ counts, const int* __restrict__ partial,
                             int N, int* __restrict__ offsets, int* __restrict__ cursor) {
    __shared__ int sm[256];
    int t = threadIdx.x, i = blockIdx.x * 256 + t;
    int v = (i < N) ? counts[i] : 0;
    sm[t] = v;
    __syncthreads();
    for (int s = 1; s < 256; s <<= 1) {
        int add = (t >= s) ? sm[t - s] : 0;
        __syncthreads();
        sm[t] += add;
        __syncthreads();
    }
    if (i < N) {
        int ex = partial[blockIdx.x] + sm[t] - v;  // exclusive
        offsets[i] = ex;
        cursor[i] = ex;
    }
}

// scatter: pidx[p] = etype[e]*N + src[e] at dst-sorted position p
__global__ void scatter_kernel(const int* __restrict__ dst, const int* __restrict__ src,
                               const int* __restrict__ etypes, int E, int N,
                               int* __restrict__ cursor, int* __restrict__ pidx) {
    int e = blockIdx.x * 256 + threadIdx.x;
    if (e < E) {
        int pos = atomicAdd(&cursor[dst[e]], 1);
        pidx[pos] = etypes[e] * N + src[e];
    }
}

// ---- segmented gather-reduce over permuted proj rows ----
// out[v][col] = sum_{j in [offsets[v],offsets[v+1])} projb[pidx[j]][c'],
// unpermuted at the final write: col = (c'&3)*16 + (c'>>2).
__global__ __launch_bounds__(256)
void reduce_kernel(const int* __restrict__ offsets, const int* __restrict__ pidx,
                   const __bf16* __restrict__ projb, int N, float* __restrict__ out) {
    int gid = blockIdx.x * 256 + threadIdx.x;
    int w = gid >> 6, lane = gid & 63;
    int nw = (gridDim.x * 256) >> 6;
    int sub = lane >> 3, c8 = lane & 7;
    for (int v = w; v < N; v += nw) {
        int j0 = offsets[v], j1 = offsets[v + 1];
        float acc[8] = {0.f, 0.f, 0.f, 0.f, 0.f, 0.f, 0.f, 0.f};
        for (int j = j0 + sub; j < j1; j += 8) {
            int p = pidx[j];
            bf16x8 val = *(const bf16x8*)(projb + (size_t)p * 64 + c8 * 8);
            #pragma unroll
            for (int i = 0; i < 8; i++) acc[i] += (float)val[i];
        }
        #pragma unroll
        for (int mask = 8; mask <= 32; mask <<= 1) {
            #pragma unroll
            for (int i = 0; i < 8; i++) acc[i] += __shfl_xor(acc[i], mask, 64);
        }
        if (sub == 0) {
            float* orow = out + (size_t)v * 64;
            #pragma unroll
            for (int i = 0; i < 8; i++) {
                int cp = c8 * 8 + i;
                orow[(cp & 3) * 16 + (cp >> 2)] = acc[i];
            }
        }
    }
}

// ---- fallback: atomic scatter (R4, known-good 433us; no ws use) ----
#define TM 64
__global__ __launch_bounds__(NTHREADS)
void rgcn_atomic(const float* __restrict__ feat, const float* __restrict__ weight,
                 const int* __restrict__ src, const int* __restrict__ dst,
                 const int* __restrict__ etypes, int E,
                 float* __restrict__ out) {
    __shared__ __bf16 Wt[64 * 136];
    int b = blockIdx.x;
    int e0 = b * TM;
    int t = threadIdx.x;
    int wave = t >> 6, lane = t & 63;
    int q = lane >> 4, m = lane & 15;
    int wbase = e0 + wave * 16;
    int last = e0 + TM - 1; if (last > E - 1) last = E - 1;
    int rmin = etypes[e0];
    int rmax = etypes[last];
    int em = wbase + m;
    bool rowok = em < E;
    int ei = rowok ? em : E - 1;
    int my_et = rowok ? etypes[em] : -1;
    const float* arow = feat + (long)src[ei] * 128;
    bf16x8 a[4];
    #pragma unroll
    for (int ks = 0; ks < 4; ks++) {
        float4 fa = *(const float4*)(arow + ks * 32 + q * 8);
        float4 fb = *(const float4*)(arow + ks * 32 + q * 8 + 4);
        bf16x8 v;
        v[0] = (__bf16)fa.x; v[1] = (__bf16)fa.y;
        v[2] = (__bf16)fa.z; v[3] = (__bf16)fa.w;
        v[4] = (__bf16)fb.x; v[5] = (__bf16)fb.y;
        v[6] = (__bf16)fb.z; v[7] = (__bf16)fb.w;
        a[ks] = v;
    }
    f32x4 acc0 = {0.f, 0.f, 0.f, 0.f};
    f32x4 acc1 = {0.f, 0.f, 0.f, 0.f};
    f32x4 acc2 = {0.f, 0.f, 0.f, 0.f};
    f32x4 acc3 = {0.f, 0.f, 0.f, 0.f};
    for (int r = rmin; r <= rmax; ++r) {
        if (r != rmin) __syncthreads();
        const float* wg = weight + (r << 13);
        for (int p = t; p < 4096; p += NTHREADS) {
            int n = p & 63, kh = p >> 6;
            float w0 = wg[(kh * 2) * 64 + n];
            float w1 = wg[(kh * 2 + 1) * 64 + n];
            union { unsigned u; __bf16 h[2]; } pk;
            pk.h[0] = (__bf16)w0; pk.h[1] = (__bf16)w1;
            *(unsigned*)&Wt[n * 136 + kh * 2] = pk.u;
        }
        __syncthreads();
        bool on = (my_et == r);
        #pragma unroll
        for (int ks = 0; ks < 4; ks++) {
            bf16x8 af = a[ks];
            if (!on) {
                #pragma unroll
                for (int j = 0; j < 8; j++) af[j] = (__bf16)0.f;
            }
            bf16x8 b0 = *(const bf16x8*)(&Wt[(0 * 16 + m) * 136 + ks * 32 + q * 8]);
            bf16x8 b1 = *(const bf16x8*)(&Wt[(1 * 16 + m) * 136 + ks * 32 + q * 8]);
            bf16x8 b2 = *(const bf16x8*)(&Wt[(2 * 16 + m) * 136 + ks * 32 + q * 8]);
            bf16x8 b3 = *(const bf16x8*)(&Wt[(3 * 16 + m) * 136 + ks * 32 + q * 8]);
            acc0 = __builtin_amdgcn_mfma_f32_16x16x32_bf16(af, b0, acc0, 0, 0, 0);
            acc1 = __builtin_amdgcn_mfma_f32_16x16x32_bf16(af, b1, acc1, 0, 0, 0);
            acc2 = __builtin_amdgcn_mfma_f32_16x16x32_bf16(af, b2, acc2, 0, 0, 0);
            acc3 = __builtin_amdgcn_mfma_f32_16x16x32_bf16(af, b3, acc3, 0, 0, 0);
        }
    }
    #pragma unroll
    for (int reg = 0; reg < 4; reg++) {
        int er = wbase + q * 4 + reg;
        if (er < E) {
            float* orow = out + (long)dst[er] * 64;
            unsafeAtomicAdd(orow + 0 * 16 + m, acc0[reg]);
            unsafeAtomicAdd(orow + 1 * 16 + m, acc1[reg]);
            unsafeAtomicAdd(orow + 2 * 16 + m, acc2[reg]);
            unsafeAtomicAdd(orow + 3 * 16 + m, acc3[reg]);
        }
    }
}

extern "C" void kernel_launch(void* const* d_in, const int* in_sizes, int n_in,
                              void* d_out, int out_size, void* d_ws, size_t ws_size,
                              hipStream_t stream) {
    const float* feat   = (const float*)d_in[0];
    const float* weight = (const float*)d_in[1];
    const int*   src    = (const int*)d_in[2];
    const int*   dst    = (const int*)d_in[3];
    const int*   etypes = (const int*)d_in[4];
    float* out = (float*)d_out;

    int nfeat = in_sizes[0];
    int nw    = in_sizes[1];
    int E     = in_sizes[2];
    int N     = nfeat / 128;
    int R     = nw >> 13;          // nw / (128*64)
    int NB    = (N + 255) / 256;

    // ws layout (256B-aligned slabs)
    size_t o = 0;
    auto take = [&](size_t bytes) { size_t r = o; o = (o + bytes + 255) & ~(size_t)255; return r; };
    size_t o_counts  = take((size_t)(N + 1) * 4);
    size_t o_offsets = take((size_t)(N + 1) * 4);
    size_t o_cursor  = take((size_t)N * 4);
    size_t o_partial = take((size_t)NB * 4);
    size_t o_pidx    = take((size_t)E * 4);
    size_t o_wtb     = take((size_t)nw * 2);
    size_t o_featb   = take((size_t)nfeat * 2);
    size_t o_projb   = take((size_t)R * N * 64 * 2);
    size_t need = o;

    int egrid = (E + 255) / 256;

    if (ws_size >= need && NB <= 512) {
        char* ws = (char*)d_ws;
        int* counts  = (int*)(ws + o_counts);
        int* offsets = (int*)(ws + o_offsets);
        int* cursor  = (int*)(ws + o_cursor);
        int* partial = (int*)(ws + o_partial);
        int* pidx    = (int*)(ws + o_pidx);
        __bf16* wtb   = (__bf16*)(ws + o_wtb);
        __bf16* featb = (__bf16*)(ws + o_featb);
        __bf16* projb = (__bf16*)(ws + o_projb);

        hipMemsetAsync(counts, 0, (size_t)(N + 1) * 4, stream);
        hist_kernel<<<egrid, 256, 0, stream>>>(dst, E, counts);
        scan1_kernel<<<NB, 256, 0, stream>>>(counts, N, partial);
        scan2_kernel<<<1, 512, 0, stream>>>(partial, NB, offsets, N, E);
        scan3_kernel<<<NB, 256, 0, stream>>>(counts, partial, N, offsets, cursor);
        scatter_kernel<<<egrid, 256, 0, stream>>>(dst, src, etypes, E, N, cursor, pidx);
        cvt_w_kernel<<<(nw + 255) / 256, 256, 0, stream>>>(weight, wtb, nw);
        cvt_feat_kernel<<<(nfeat / 8 + 255) / 256, 256, 0, stream>>>(feat, featb, nfeat);

        dim3 pgrid((N + 127) / 128, R);
        proj_kernel<<<pgrid, NTHREADS, 0, stream>>>(featb, wtb, N, projb);
        reduce_kernel<<<2048, 256, 0, stream>>>(offsets, pidx, projb, N, out);
    } else {
        hipMemsetAsync(d_out, 0, (size_t)out_size * sizeof(float), stream);
        int mgrid = (E + TM - 1) / TM;
        rgcn_atomic<<<mgrid, NTHREADS, 0, stream>>>(feat, weight, src, dst, etypes, E, out);
    }
}